// Round 1
// baseline (289.612 us; speedup 1.0000x reference)
//
#include <hip/hip_runtime.h>
#include <hip/hip_bf16.h>
#include <math.h>

typedef __attribute__((ext_vector_type(8))) short short8;
typedef __attribute__((ext_vector_type(4))) float f32x4;

#define NUM_TABLES 26
#define ROWS 100000
#define EMB 64
#define BATCH 4096
#define LOOKUPS 32
#define ZDIM 1728  // 64*(1+26)

__device__ __forceinline__ unsigned short f2bf(float f) {
  unsigned int u = __float_as_uint(f);
  u += 0x7FFFu + ((u >> 16) & 1u);   // round-to-nearest-even
  return (unsigned short)(u >> 16);
}
__device__ __forceinline__ float bf2f(unsigned short h) {
  return __uint_as_float(((unsigned int)h) << 16);
}

// ---- cast f32 -> bf16 (n divisible by 4) ----
__global__ void cast_bf16_kernel(const float* __restrict__ src,
                                 unsigned short* __restrict__ dst, int n4) {
  int i = blockIdx.x * blockDim.x + threadIdx.x;
  if (i >= n4) return;
  float4 v = ((const float4*)src)[i];
  ushort4 o;
  o.x = f2bf(v.x); o.y = f2bf(v.y); o.z = f2bf(v.z); o.w = f2bf(v.w);
  ((ushort4*)dst)[i] = o;
}

// ---- GEMM: C[M,N] = act(A[M,K] @ W[N,K]^T + bias), all bf16 in, bf16 out ----
// one wave per 16x16 output tile; MFMA 16x16x32 bf16.
// A-frag: lane l holds A[tileM + (l&15)][ (l>>4)*8 + j ], j=0..7 (16B contig)
// B-frag: lane l holds W[tileN + (l&15)][ (l>>4)*8 + j ]  (B[k][n] = W[n][k])
// D: lane l, reg r -> row (l>>4)*4 + r, col l&15
template<int ACT>  // 0 = none, 1 = relu
__global__ void gemm16(const unsigned short* __restrict__ A,
                       const unsigned short* __restrict__ W,
                       const float* __restrict__ bias,
                       unsigned short* __restrict__ C,
                       int M, int N, int K, int ldc) {
  int lane = threadIdx.x & 63;
  int gw = (int)((blockIdx.x * blockDim.x + threadIdx.x) >> 6);
  int ntn = N >> 4;
  int tm = gw / ntn;
  int tn = gw - tm * ntn;
  if (tm >= (M >> 4)) return;

  int arow = (tm << 4) + (lane & 15);
  int wrow = (tn << 4) + (lane & 15);
  int kb = (lane >> 4) << 3;

  const short8* Ap = (const short8*)(A + (size_t)arow * K + kb);
  const short8* Wp = (const short8*)(W + (size_t)wrow * K + kb);

  f32x4 acc = {0.f, 0.f, 0.f, 0.f};
  int steps = K >> 5;
  #pragma unroll 4
  for (int s = 0; s < steps; ++s) {
    short8 a = Ap[s * 4];   // advance 32 bf16 per step
    short8 b = Wp[s * 4];
    acc = __builtin_amdgcn_mfma_f32_16x16x32_bf16(a, b, acc, 0, 0, 0);
  }

  int dcol = (tn << 4) + (lane & 15);
  int drow = (tm << 4) + ((lane >> 4) << 2);
  float bv = bias[dcol];
  #pragma unroll
  for (int r = 0; r < 4; ++r) {
    float v = acc[r] + bv;
    if (ACT == 1) v = v > 0.f ? v : 0.f;
    C[(size_t)(drow + r) * ldc + dcol] = f2bf(v);
  }
}

// ---- EmbeddingBag sum: one wave per (table, sample) bag; lane = emb element ----
__global__ void embed_pool(const int* __restrict__ idx,
                           const float* __restrict__ tables,
                           unsigned short* __restrict__ z) {
  int g = (int)((blockIdx.x * blockDim.x + threadIdx.x) >> 6);
  int lane = threadIdx.x & 63;
  int t = g >> 12;          // / 4096
  int b = g & 4095;
  const int* ip = idx + ((size_t)t * BATCH + b) * LOOKUPS;
  int myidx = (lane < LOOKUPS) ? ip[lane] : 0;
  const float* tbl = tables + (size_t)t * ROWS * EMB;
  float acc = 0.f;
  #pragma unroll
  for (int l = 0; l < LOOKUPS; ++l) {
    int r = __shfl(myidx, l, 64);
    acc += tbl[(size_t)r * EMB + lane];
  }
  z[(size_t)b * ZDIM + EMB + t * EMB + lane] = f2bf(acc);
}

// ---- final layer: out[b] = sigmoid(dot(z2[b,0:256], w) + bias) ----
__global__ void final_layer(const unsigned short* __restrict__ z2,
                            const float* __restrict__ w,
                            const float* __restrict__ bias,
                            float* __restrict__ out) {
  int g = (int)((blockIdx.x * blockDim.x + threadIdx.x) >> 6);  // sample
  int lane = threadIdx.x & 63;
  const unsigned short* zp = z2 + (size_t)g * 256;
  float s = 0.f;
  #pragma unroll
  for (int k = 0; k < 256; k += 64)
    s += bf2f(zp[k + lane]) * w[k + lane];
  #pragma unroll
  for (int off = 32; off > 0; off >>= 1)
    s += __shfl_down(s, off, 64);
  if (lane == 0) out[g] = 1.f / (1.f + expf(-(s + bias[0])));
}

extern "C" void kernel_launch(void* const* d_in, const int* in_sizes, int n_in,
                              void* d_out, int out_size, void* d_ws, size_t ws_size,
                              hipStream_t stream) {
  const float* x_dense = (const float*)d_in[0];
  const int*   x_idx   = (const int*)d_in[1];
  const float* tables  = (const float*)d_in[2];
  const float* bw0 = (const float*)d_in[3];  const float* bb0 = (const float*)d_in[4];
  const float* bw1 = (const float*)d_in[5];  const float* bb1 = (const float*)d_in[6];
  const float* bw2 = (const float*)d_in[7];  const float* bb2 = (const float*)d_in[8];
  const float* tw0 = (const float*)d_in[9];  const float* tb0 = (const float*)d_in[10];
  const float* tw1 = (const float*)d_in[11]; const float* tb1 = (const float*)d_in[12];
  const float* tw2 = (const float*)d_in[13]; const float* tb2 = (const float*)d_in[14];
  float* out = (float*)d_out;

  char* ws = (char*)d_ws;
  size_t off = 0;
  auto alloc = [&](size_t bytes) { void* p = ws + off; off += (bytes + 255) & ~(size_t)255; return p; };
  unsigned short* xdb  = (unsigned short*)alloc((size_t)BATCH * 256 * 2);
  unsigned short* bw0b = (unsigned short*)alloc((size_t)512 * 256 * 2);
  unsigned short* bw1b = (unsigned short*)alloc((size_t)256 * 512 * 2);
  unsigned short* bw2b = (unsigned short*)alloc((size_t)64 * 256 * 2);
  unsigned short* tw0b = (unsigned short*)alloc((size_t)512 * ZDIM * 2);
  unsigned short* tw1b = (unsigned short*)alloc((size_t)256 * 512 * 2);
  unsigned short* h0   = (unsigned short*)alloc((size_t)BATCH * 512 * 2);
  unsigned short* h1   = (unsigned short*)alloc((size_t)BATCH * 256 * 2);
  unsigned short* z    = (unsigned short*)alloc((size_t)BATCH * ZDIM * 2);
  unsigned short* z1   = (unsigned short*)alloc((size_t)BATCH * 512 * 2);
  unsigned short* z2   = (unsigned short*)alloc((size_t)BATCH * 256 * 2);

  auto cast = [&](const float* s, unsigned short* d, int n) {
    int n4 = n >> 2;
    cast_bf16_kernel<<<(n4 + 255) / 256, 256, 0, stream>>>(s, d, n4);
  };
  cast(x_dense, xdb, BATCH * 256);
  cast(bw0, bw0b, 512 * 256);
  cast(bw1, bw1b, 256 * 512);
  cast(bw2, bw2b, 64 * 256);
  cast(tw0, tw0b, 512 * ZDIM);
  cast(tw1, tw1b, 256 * 512);

  // embedding pooling -> z[:, 64:1728]
  {
    int waves = NUM_TABLES * BATCH;       // 106496
    embed_pool<<<waves / 4, 256, 0, stream>>>(x_idx, tables, z);
  }

  auto gemm = [&](const unsigned short* A, const unsigned short* W, const float* bias,
                  unsigned short* C, int M, int N, int K, int ldc, int relu) {
    int tiles = (M >> 4) * (N >> 4);
    if (relu)
      gemm16<1><<<tiles / 4, 256, 0, stream>>>(A, W, bias, C, M, N, K, ldc);
    else
      gemm16<0><<<tiles / 4, 256, 0, stream>>>(A, W, bias, C, M, N, K, ldc);
  };

  // bottom MLP
  gemm(xdb, bw0b, bb0, h0, BATCH, 512, 256, 512, 1);
  gemm(h0,  bw1b, bb1, h1, BATCH, 256, 512, 256, 1);
  gemm(h1,  bw2b, bb2, z,  BATCH, 64, 256, ZDIM, 1);   // into z[:,0:64]

  // top MLP
  gemm(z,  tw0b, tb0, z1, BATCH, 512, ZDIM, 512, 1);
  gemm(z1, tw1b, tb1, z2, BATCH, 256, 512, 256, 1);

  final_layer<<<BATCH / 4, 256, 0, stream>>>(z2, tw2, tb2, out);
}

// Round 2
// 228.092 us; speedup vs baseline: 1.2697x; 1.2697x over previous
//
#include <hip/hip_runtime.h>
#include <hip/hip_bf16.h>
#include <math.h>

typedef __attribute__((ext_vector_type(8))) short short8;
typedef __attribute__((ext_vector_type(4))) float f32x4;

#define NUM_TABLES 26
#define ROWS 100000
#define EMB 64
#define BATCH 4096
#define LOOKUPS 32
#define ZDIM 1728  // 64*(1+26)

__device__ __forceinline__ unsigned short f2bf(float f) {
  unsigned int u = __float_as_uint(f);
  u += 0x7FFFu + ((u >> 16) & 1u);   // round-to-nearest-even
  return (unsigned short)(u >> 16);
}
__device__ __forceinline__ float bf2f(unsigned short h) {
  return __uint_as_float(((unsigned int)h) << 16);
}

// ---- merged cast f32 -> bf16 over 6 segments ----
struct CastArgs {
  const float* s[6];
  unsigned short* d[6];
  int n4[6];      // float4 counts
  int total;
};

__global__ void cast_all_kernel(CastArgs a) {
  for (int i = blockIdx.x * blockDim.x + threadIdx.x; i < a.total;
       i += gridDim.x * blockDim.x) {
    int r = i;
    #pragma unroll
    for (int sg = 0; sg < 6; ++sg) {
      if (r < a.n4[sg]) {
        float4 v = ((const float4*)a.s[sg])[r];
        ushort4 o;
        o.x = f2bf(v.x); o.y = f2bf(v.y); o.z = f2bf(v.z); o.w = f2bf(v.w);
        ((ushort4*)a.d[sg])[r] = o;
        break;
      }
      r -= a.n4[sg];
    }
  }
}

// ---- block GEMM: C[M,N] = act(A[M,K] @ W[N,K]^T + bias) ----
// 64x64 tile per 256-thread block (4 waves), K-step 64, LDS-staged.
// Wave (wr,wc) computes 32x32 quadrant = 2x2 16x16 MFMA frags.
// LDS rows padded to 72 elems (144B) to spread banks on ds_read_b128.
template<int ACT>  // 0 = none, 1 = relu
__global__ __launch_bounds__(256) void gemm64(
    const unsigned short* __restrict__ A,
    const unsigned short* __restrict__ W,
    const float* __restrict__ bias,
    unsigned short* __restrict__ C,
    int M, int N, int K, int ldc) {
  __shared__ unsigned short ldsA[64][72];
  __shared__ unsigned short ldsB[64][72];

  int t = threadIdx.x;
  int lane = t & 63;
  int wid = t >> 6;
  int wr = wid >> 1;        // 0..1
  int wc = wid & 1;         // 0..1

  int ntn = N >> 6;
  int tm = blockIdx.x / ntn;
  int tn = blockIdx.x - tm * ntn;

  // staging coords: each thread stages 2 chunks of 16B per matrix
  int row0 = t >> 3;            // chunk t: rows 0..31
  int cc0  = t & 7;
  int row1 = row0 + 32;         // chunk t+256

  const unsigned short* Ab = A + (size_t)(tm * 64) * K;
  const unsigned short* Wb = W + (size_t)(tn * 64) * K;

  f32x4 acc[2][2];
  #pragma unroll
  for (int m = 0; m < 2; ++m)
    #pragma unroll
    for (int n = 0; n < 2; ++n)
      acc[m][n] = (f32x4){0.f, 0.f, 0.f, 0.f};

  int arow_f = wr * 32 + (lane & 15);   // frag base row in tile (A)
  int brow_f = wc * 32 + (lane & 15);
  int kf = (lane >> 4) << 3;            // 0,8,16,24

  for (int k0 = 0; k0 < K; k0 += 64) {
    // stage A and B tiles (reg -> LDS, padded rows)
    *(short8*)&ldsA[row0][cc0 * 8] = *(const short8*)(Ab + (size_t)row0 * K + k0 + cc0 * 8);
    *(short8*)&ldsA[row1][cc0 * 8] = *(const short8*)(Ab + (size_t)row1 * K + k0 + cc0 * 8);
    *(short8*)&ldsB[row0][cc0 * 8] = *(const short8*)(Wb + (size_t)row0 * K + k0 + cc0 * 8);
    *(short8*)&ldsB[row1][cc0 * 8] = *(const short8*)(Wb + (size_t)row1 * K + k0 + cc0 * 8);
    __syncthreads();

    #pragma unroll
    for (int kc = 0; kc < 2; ++kc) {
      short8 a0 = *(const short8*)&ldsA[arow_f][kc * 32 + kf];
      short8 a1 = *(const short8*)&ldsA[arow_f + 16][kc * 32 + kf];
      short8 b0 = *(const short8*)&ldsB[brow_f][kc * 32 + kf];
      short8 b1 = *(const short8*)&ldsB[brow_f + 16][kc * 32 + kf];
      acc[0][0] = __builtin_amdgcn_mfma_f32_16x16x32_bf16(a0, b0, acc[0][0], 0, 0, 0);
      acc[0][1] = __builtin_amdgcn_mfma_f32_16x16x32_bf16(a0, b1, acc[0][1], 0, 0, 0);
      acc[1][0] = __builtin_amdgcn_mfma_f32_16x16x32_bf16(a1, b0, acc[1][0], 0, 0, 0);
      acc[1][1] = __builtin_amdgcn_mfma_f32_16x16x32_bf16(a1, b1, acc[1][1], 0, 0, 0);
    }
    __syncthreads();
  }

  // epilogue
  #pragma unroll
  for (int m = 0; m < 2; ++m) {
    int drow = tm * 64 + wr * 32 + m * 16 + ((lane >> 4) << 2);
    #pragma unroll
    for (int n = 0; n < 2; ++n) {
      int dcol = tn * 64 + wc * 32 + n * 16 + (lane & 15);
      float bv = bias[dcol];
      #pragma unroll
      for (int r = 0; r < 4; ++r) {
        float v = acc[m][n][r] + bv;
        if (ACT == 1) v = v > 0.f ? v : 0.f;
        C[(size_t)(drow + r) * ldc + dcol] = f2bf(v);
      }
    }
  }
}

// ---- direct per-wave GEMM for small N (bot2: N=64) ----
template<int ACT>
__global__ void gemm16(const unsigned short* __restrict__ A,
                       const unsigned short* __restrict__ W,
                       const float* __restrict__ bias,
                       unsigned short* __restrict__ C,
                       int M, int N, int K, int ldc) {
  int lane = threadIdx.x & 63;
  int gw = (int)((blockIdx.x * blockDim.x + threadIdx.x) >> 6);
  int ntn = N >> 4;
  int tm = gw / ntn;
  int tn = gw - tm * ntn;
  if (tm >= (M >> 4)) return;

  int arow = (tm << 4) + (lane & 15);
  int wrow = (tn << 4) + (lane & 15);
  int kb = (lane >> 4) << 3;

  const short8* Ap = (const short8*)(A + (size_t)arow * K + kb);
  const short8* Wp = (const short8*)(W + (size_t)wrow * K + kb);

  f32x4 acc = {0.f, 0.f, 0.f, 0.f};
  int steps = K >> 5;
  #pragma unroll 8
  for (int s = 0; s < steps; ++s) {
    short8 a = Ap[s * 4];
    short8 b = Wp[s * 4];
    acc = __builtin_amdgcn_mfma_f32_16x16x32_bf16(a, b, acc, 0, 0, 0);
  }

  int dcol = (tn << 4) + (lane & 15);
  int drow = (tm << 4) + ((lane >> 4) << 2);
  float bv = bias[dcol];
  #pragma unroll
  for (int r = 0; r < 4; ++r) {
    float v = acc[r] + bv;
    if (ACT == 1) v = v > 0.f ? v : 0.f;
    C[(size_t)(drow + r) * ldc + dcol] = f2bf(v);
  }
}

// ---- EmbeddingBag sum, vectorized: wave per bag, float4/lane, 4 rows/iter ----
__global__ void embed_pool(const int* __restrict__ idx,
                           const float* __restrict__ tables,
                           unsigned short* __restrict__ z) {
  int g = (int)((blockIdx.x * blockDim.x + threadIdx.x) >> 6);  // bag id
  int lane = threadIdx.x & 63;
  int t = g >> 12;          // / BATCH
  int b = g & 4095;
  const int* ip = idx + ((size_t)t * BATCH + b) * LOOKUPS;
  int myidx = (lane < LOOKUPS) ? ip[lane] : 0;
  const float* tbl = tables + (size_t)t * ROWS * EMB;
  int grp = lane >> 4;      // lookup sub-group 0..3
  int e4 = lane & 15;       // float4 index within row
  float4 acc = {0.f, 0.f, 0.f, 0.f};
  #pragma unroll
  for (int it = 0; it < 8; ++it) {
    int r = __shfl(myidx, it * 4 + grp, 64);
    float4 v = ((const float4*)(tbl + (size_t)r * EMB))[e4];
    acc.x += v.x; acc.y += v.y; acc.z += v.z; acc.w += v.w;
  }
  // reduce across the 4 lookup groups (lanes l, l^16, l^32)
  #pragma unroll
  for (int m = 16; m <= 32; m <<= 1) {
    acc.x += __shfl_xor(acc.x, m, 64);
    acc.y += __shfl_xor(acc.y, m, 64);
    acc.z += __shfl_xor(acc.z, m, 64);
    acc.w += __shfl_xor(acc.w, m, 64);
  }
  if (lane < 16) {
    ushort4 o;
    o.x = f2bf(acc.x); o.y = f2bf(acc.y); o.z = f2bf(acc.z); o.w = f2bf(acc.w);
    *(ushort4*)&z[(size_t)b * ZDIM + EMB + t * EMB + e4 * 4] = o;
  }
}

// ---- final layer: out[b] = sigmoid(dot(z2[b,0:256], w) + bias) ----
__global__ void final_layer(const unsigned short* __restrict__ z2,
                            const float* __restrict__ w,
                            const float* __restrict__ bias,
                            float* __restrict__ out) {
  int g = (int)((blockIdx.x * blockDim.x + threadIdx.x) >> 6);  // sample
  int lane = threadIdx.x & 63;
  const unsigned short* zp = z2 + (size_t)g * 256;
  float s = 0.f;
  #pragma unroll
  for (int k = 0; k < 256; k += 64)
    s += bf2f(zp[k + lane]) * w[k + lane];
  #pragma unroll
  for (int off = 32; off > 0; off >>= 1)
    s += __shfl_down(s, off, 64);
  if (lane == 0) out[g] = 1.f / (1.f + expf(-(s + bias[0])));
}

extern "C" void kernel_launch(void* const* d_in, const int* in_sizes, int n_in,
                              void* d_out, int out_size, void* d_ws, size_t ws_size,
                              hipStream_t stream) {
  const float* x_dense = (const float*)d_in[0];
  const int*   x_idx   = (const int*)d_in[1];
  const float* tables  = (const float*)d_in[2];
  const float* bw0 = (const float*)d_in[3];  const float* bb0 = (const float*)d_in[4];
  const float* bw1 = (const float*)d_in[5];  const float* bb1 = (const float*)d_in[6];
  const float* bw2 = (const float*)d_in[7];  const float* bb2 = (const float*)d_in[8];
  const float* tw0 = (const float*)d_in[9];  const float* tb0 = (const float*)d_in[10];
  const float* tw1 = (const float*)d_in[11]; const float* tb1 = (const float*)d_in[12];
  const float* tw2 = (const float*)d_in[13]; const float* tb2 = (const float*)d_in[14];
  float* out = (float*)d_out;

  char* ws = (char*)d_ws;
  size_t off = 0;
  auto alloc = [&](size_t bytes) { void* p = ws + off; off += (bytes + 255) & ~(size_t)255; return p; };
  unsigned short* xdb  = (unsigned short*)alloc((size_t)BATCH * 256 * 2);
  unsigned short* bw0b = (unsigned short*)alloc((size_t)512 * 256 * 2);
  unsigned short* bw1b = (unsigned short*)alloc((size_t)256 * 512 * 2);
  unsigned short* bw2b = (unsigned short*)alloc((size_t)64 * 256 * 2);
  unsigned short* tw0b = (unsigned short*)alloc((size_t)512 * ZDIM * 2);
  unsigned short* tw1b = (unsigned short*)alloc((size_t)256 * 512 * 2);
  unsigned short* h0   = (unsigned short*)alloc((size_t)BATCH * 512 * 2);
  unsigned short* h1   = (unsigned short*)alloc((size_t)BATCH * 256 * 2);
  unsigned short* z    = (unsigned short*)alloc((size_t)BATCH * ZDIM * 2);
  unsigned short* z1   = (unsigned short*)alloc((size_t)BATCH * 512 * 2);
  unsigned short* z2   = (unsigned short*)alloc((size_t)BATCH * 256 * 2);

  // merged casts
  {
    CastArgs a;
    a.s[0] = x_dense; a.d[0] = xdb;  a.n4[0] = BATCH * 256 / 4;
    a.s[1] = bw0;     a.d[1] = bw0b; a.n4[1] = 512 * 256 / 4;
    a.s[2] = bw1;     a.d[2] = bw1b; a.n4[2] = 256 * 512 / 4;
    a.s[3] = bw2;     a.d[3] = bw2b; a.n4[3] = 64 * 256 / 4;
    a.s[4] = tw0;     a.d[4] = tw0b; a.n4[4] = 512 * ZDIM / 4;
    a.s[5] = tw1;     a.d[5] = tw1b; a.n4[5] = 256 * 512 / 4;
    a.total = a.n4[0] + a.n4[1] + a.n4[2] + a.n4[3] + a.n4[4] + a.n4[5];
    cast_all_kernel<<<2048, 256, 0, stream>>>(a);
  }

  // embedding pooling -> z[:, 64:1728]
  {
    int waves = NUM_TABLES * BATCH;       // 106496
    embed_pool<<<waves / 4, 256, 0, stream>>>(x_idx, tables, z);
  }

  auto gemm = [&](const unsigned short* A, const unsigned short* W, const float* bias,
                  unsigned short* C, int M, int N, int K, int ldc, int relu) {
    if (N >= 128) {
      int blocks = (M >> 6) * (N >> 6);
      if (relu)
        gemm64<1><<<blocks, 256, 0, stream>>>(A, W, bias, C, M, N, K, ldc);
      else
        gemm64<0><<<blocks, 256, 0, stream>>>(A, W, bias, C, M, N, K, ldc);
    } else {
      int tiles = (M >> 4) * (N >> 4);
      if (relu)
        gemm16<1><<<tiles / 4, 256, 0, stream>>>(A, W, bias, C, M, N, K, ldc);
      else
        gemm16<0><<<tiles / 4, 256, 0, stream>>>(A, W, bias, C, M, N, K, ldc);
    }
  };

  // bottom MLP
  gemm(xdb, bw0b, bb0, h0, BATCH, 512, 256, 512, 1);
  gemm(h0,  bw1b, bb1, h1, BATCH, 256, 512, 256, 1);
  gemm(h1,  bw2b, bb2, z,  BATCH, 64, 256, ZDIM, 1);   // into z[:,0:64]

  // top MLP
  gemm(z,  tw0b, tb0, z1, BATCH, 512, ZDIM, 512, 1);
  gemm(z1, tw1b, tb1, z2, BATCH, 256, 512, 256, 1);

  final_layer<<<BATCH / 4, 256, 0, stream>>>(z2, tw2, tb2, out);
}

// Round 4
// 182.248 us; speedup vs baseline: 1.5891x; 1.2516x over previous
//
#include <hip/hip_runtime.h>
#include <hip/hip_bf16.h>
#include <math.h>

typedef __attribute__((ext_vector_type(8))) short short8;
typedef __attribute__((ext_vector_type(4))) float f32x4;

#define NUM_TABLES 26
#define ROWS 100000
#define EMB 64
#define BATCH 4096
#define LOOKUPS 32
#define ZDIM 1728  // 64*(1+26)
#define CAST_BLOCKS 512
#define EMBED_BLOCKS (NUM_TABLES * BATCH / 4)

__device__ __forceinline__ unsigned short f2bf(float f) {
  unsigned int u = __float_as_uint(f);
  u += 0x7FFFu + ((u >> 16) & 1u);   // round-to-nearest-even
  return (unsigned short)(u >> 16);
}
__device__ __forceinline__ float bf2f(unsigned short h) {
  return __uint_as_float(((unsigned int)h) << 16);
}

__device__ __forceinline__ void gload16(const void* g, void* l) {
  __builtin_amdgcn_global_load_lds(
      (const __attribute__((address_space(1))) void*)g,
      (__attribute__((address_space(3))) void*)l, 16, 0, 0);
}

// ---- merged cast f32 -> bf16 over 6 segments ----
struct CastArgs {
  const float* s[6];
  unsigned short* d[6];
  int n4[6];      // float4 counts
  int total;
};

// ---- fused: blocks [0,CAST_BLOCKS) cast weights; rest do EmbeddingBag sum ----
__global__ void embed_cast(CastArgs a, const int* __restrict__ idx,
                           const float* __restrict__ tables,
                           unsigned short* __restrict__ z) {
  if (blockIdx.x < CAST_BLOCKS) {
    for (int i = blockIdx.x * blockDim.x + threadIdx.x; i < a.total;
         i += CAST_BLOCKS * blockDim.x) {
      int r = i;
      #pragma unroll
      for (int sg = 0; sg < 6; ++sg) {
        if (r < a.n4[sg]) {
          float4 v = ((const float4*)a.s[sg])[r];
          ushort4 o;
          o.x = f2bf(v.x); o.y = f2bf(v.y); o.z = f2bf(v.z); o.w = f2bf(v.w);
          ((ushort4*)a.d[sg])[r] = o;
          break;
        }
        r -= a.n4[sg];
      }
    }
    return;
  }
  // embedding role: one wave per bag, float4/lane, 4 rows/iter
  int g = (int)(((blockIdx.x - CAST_BLOCKS) << 2) + (threadIdx.x >> 6));
  int lane = threadIdx.x & 63;
  int t = g >> 12;          // / BATCH
  int b = g & 4095;
  const int* ip = idx + ((size_t)t * BATCH + b) * LOOKUPS;
  int myidx = (lane < LOOKUPS) ? ip[lane] : 0;
  const float* tbl = tables + (size_t)t * ROWS * EMB;
  int grp = lane >> 4;      // lookup sub-group 0..3
  int e4 = lane & 15;       // float4 index within row
  float4 acc = {0.f, 0.f, 0.f, 0.f};
  #pragma unroll
  for (int it = 0; it < 8; ++it) {
    int r = __shfl(myidx, it * 4 + grp, 64);
    float4 v = ((const float4*)(tbl + (size_t)r * EMB))[e4];
    acc.x += v.x; acc.y += v.y; acc.z += v.z; acc.w += v.w;
  }
  #pragma unroll
  for (int m = 16; m <= 32; m <<= 1) {
    acc.x += __shfl_xor(acc.x, m, 64);
    acc.y += __shfl_xor(acc.y, m, 64);
    acc.z += __shfl_xor(acc.z, m, 64);
    acc.w += __shfl_xor(acc.w, m, 64);
  }
  if (lane < 16) {
    ushort4 o;
    o.x = f2bf(acc.x); o.y = f2bf(acc.y); o.z = f2bf(acc.z); o.w = f2bf(acc.w);
    *(ushort4*)&z[(size_t)b * ZDIM + EMB + t * EMB + e4 * 4] = o;
  }
}

// ---- block GEMM (m97 single-buffer schedule): C = act(A @ W^T + bias) ----
// 64x64 tile / 256-thread block, K-step 64. Staging via global_load_lds
// (width 16, linear LDS dest). Bank-swizzle via pre-swizzled GLOBAL source:
// LDS[r][chunk c] = global[r][c ^ (r&7)]; read applies the same XOR.
// Schedule per K-step: stage -> syncthreads -> ds_read+MFMA -> syncthreads.
// (Double-buffer variant raced under graph replay in R3 — keep single-buffer.)
template<int ACT>  // 0 = none, 1 = relu
__global__ __launch_bounds__(256) void gemm64s(
    const unsigned short* __restrict__ A,
    const unsigned short* __restrict__ W,
    const float* __restrict__ bias,
    unsigned short* __restrict__ C,
    int M, int N, int K, int ldc) {
  __shared__ unsigned short lds[2][64][64];  // [A=0/B=1][row][col], 16 KiB

  int t = threadIdx.x;
  int lane = t & 63;
  int wid = t >> 6;
  int wr = wid >> 1;        // 0..1
  int wc = wid & 1;         // 0..1

  int ntn = N >> 6;
  int tm = blockIdx.x / ntn;
  int tn = blockIdx.x - tm * ntn;

  // staging: wave wid stages rows [wid*16, wid*16+16), 2 loads per matrix.
  // lane l, load j: row = wid*16 + j*8 + (l>>3), global chunk = (l&7)^((l>>3)&7)
  int srow = lane >> 3;
  int schunk = (lane & 7) ^ (srow & 7);
  const unsigned short* Ap0 = A + (size_t)(tm * 64 + wid * 16 + srow) * K + schunk * 8;
  const unsigned short* Wp0 = W + (size_t)(tn * 64 + wid * 16 + srow) * K + schunk * 8;
  size_t rowK8 = (size_t)8 * K;   // 8 global rows

  f32x4 acc[2][2];
  #pragma unroll
  for (int m = 0; m < 2; ++m)
    #pragma unroll
    for (int n = 0; n < 2; ++n)
      acc[m][n] = (f32x4){0.f, 0.f, 0.f, 0.f};

  int ra = wr * 32 + (lane & 15);   // A frag rows ra, ra+16
  int rb = wc * 32 + (lane & 15);   // B frag rows rb, rb+16
  int cidx = lane >> 4;             // chunk sub-index 0..3
  int sA = ra & 7, sB = rb & 7;

  for (int k0 = 0; k0 < K; k0 += 64) {
    #pragma unroll
    for (int j = 0; j < 2; ++j) {
      gload16(Ap0 + (size_t)k0 + j * rowK8, &lds[0][wid * 16 + j * 8][0]);
      gload16(Wp0 + (size_t)k0 + j * rowK8, &lds[1][wid * 16 + j * 8][0]);
    }
    __syncthreads();          // vmcnt(0)+lgkmcnt(0) drain: stage landed

    const char* bA = (const char*)&lds[0][0][0];
    const char* bB = (const char*)&lds[1][0][0];
    #pragma unroll
    for (int kc = 0; kc < 2; ++kc) {
      int c = kc * 4 + cidx;
      short8 a0 = *(const short8*)(bA + ra * 128 + ((c ^ sA) << 4));
      short8 a1 = *(const short8*)(bA + (ra + 16) * 128 + ((c ^ sA) << 4));
      short8 b0 = *(const short8*)(bB + rb * 128 + ((c ^ sB) << 4));
      short8 b1 = *(const short8*)(bB + (rb + 16) * 128 + ((c ^ sB) << 4));
      acc[0][0] = __builtin_amdgcn_mfma_f32_16x16x32_bf16(a0, b0, acc[0][0], 0, 0, 0);
      acc[0][1] = __builtin_amdgcn_mfma_f32_16x16x32_bf16(a0, b1, acc[0][1], 0, 0, 0);
      acc[1][0] = __builtin_amdgcn_mfma_f32_16x16x32_bf16(a1, b0, acc[1][0], 0, 0, 0);
      acc[1][1] = __builtin_amdgcn_mfma_f32_16x16x32_bf16(a1, b1, acc[1][1], 0, 0, 0);
    }
    __syncthreads();          // all reads done before next stage overwrites
  }

  // epilogue
  #pragma unroll
  for (int m = 0; m < 2; ++m) {
    int drow = tm * 64 + wr * 32 + m * 16 + ((lane >> 4) << 2);
    #pragma unroll
    for (int n = 0; n < 2; ++n) {
      int dcol = tn * 64 + wc * 32 + n * 16 + (lane & 15);
      float bv = bias[dcol];
      #pragma unroll
      for (int r = 0; r < 4; ++r) {
        float v = acc[m][n][r] + bv;
        if (ACT == 1) v = v > 0.f ? v : 0.f;
        C[(size_t)(drow + r) * ldc + dcol] = f2bf(v);
      }
    }
  }
}

// ---- direct per-wave GEMM for small N (bot2: N=64) ----
template<int ACT>
__global__ void gemm16(const unsigned short* __restrict__ A,
                       const unsigned short* __restrict__ W,
                       const float* __restrict__ bias,
                       unsigned short* __restrict__ C,
                       int M, int N, int K, int ldc) {
  int lane = threadIdx.x & 63;
  int gw = (int)((blockIdx.x * blockDim.x + threadIdx.x) >> 6);
  int ntn = N >> 4;
  int tm = gw / ntn;
  int tn = gw - tm * ntn;
  if (tm >= (M >> 4)) return;

  int arow = (tm << 4) + (lane & 15);
  int wrow = (tn << 4) + (lane & 15);
  int kb = (lane >> 4) << 3;

  const short8* Ap = (const short8*)(A + (size_t)arow * K + kb);
  const short8* Wp = (const short8*)(W + (size_t)wrow * K + kb);

  f32x4 acc = {0.f, 0.f, 0.f, 0.f};
  int steps = K >> 5;
  #pragma unroll 8
  for (int s = 0; s < steps; ++s) {
    short8 a = Ap[s * 4];
    short8 b = Wp[s * 4];
    acc = __builtin_amdgcn_mfma_f32_16x16x32_bf16(a, b, acc, 0, 0, 0);
  }

  int dcol = (tn << 4) + (lane & 15);
  int drow = (tm << 4) + ((lane >> 4) << 2);
  float bv = bias[dcol];
  #pragma unroll
  for (int r = 0; r < 4; ++r) {
    float v = acc[r] + bv;
    if (ACT == 1) v = v > 0.f ? v : 0.f;
    C[(size_t)(drow + r) * ldc + dcol] = f2bf(v);
  }
}

// ---- final layer: out[b] = sigmoid(dot(z2[b,0:256], w) + bias) ----
__global__ void final_layer(const unsigned short* __restrict__ z2,
                            const float* __restrict__ w,
                            const float* __restrict__ bias,
                            float* __restrict__ out) {
  int g = (int)((blockIdx.x * blockDim.x + threadIdx.x) >> 6);  // sample
  int lane = threadIdx.x & 63;
  const unsigned short* zp = z2 + (size_t)g * 256;
  float s = 0.f;
  #pragma unroll
  for (int k = 0; k < 256; k += 64)
    s += bf2f(zp[k + lane]) * w[k + lane];
  #pragma unroll
  for (int off = 32; off > 0; off >>= 1)
    s += __shfl_down(s, off, 64);
  if (lane == 0) out[g] = 1.f / (1.f + expf(-(s + bias[0])));
}

extern "C" void kernel_launch(void* const* d_in, const int* in_sizes, int n_in,
                              void* d_out, int out_size, void* d_ws, size_t ws_size,
                              hipStream_t stream) {
  const float* x_dense = (const float*)d_in[0];
  const int*   x_idx   = (const int*)d_in[1];
  const float* tables  = (const float*)d_in[2];
  const float* bw0 = (const float*)d_in[3];  const float* bb0 = (const float*)d_in[4];
  const float* bw1 = (const float*)d_in[5];  const float* bb1 = (const float*)d_in[6];
  const float* bw2 = (const float*)d_in[7];  const float* bb2 = (const float*)d_in[8];
  const float* tw0 = (const float*)d_in[9];  const float* tb0 = (const float*)d_in[10];
  const float* tw1 = (const float*)d_in[11]; const float* tb1 = (const float*)d_in[12];
  const float* tw2 = (const float*)d_in[13]; const float* tb2 = (const float*)d_in[14];
  float* out = (float*)d_out;

  char* ws = (char*)d_ws;
  size_t off = 0;
  auto alloc = [&](size_t bytes) { void* p = ws + off; off += (bytes + 255) & ~(size_t)255; return p; };
  unsigned short* xdb  = (unsigned short*)alloc((size_t)BATCH * 256 * 2);
  unsigned short* bw0b = (unsigned short*)alloc((size_t)512 * 256 * 2);
  unsigned short* bw1b = (unsigned short*)alloc((size_t)256 * 512 * 2);
  unsigned short* bw2b = (unsigned short*)alloc((size_t)64 * 256 * 2);
  unsigned short* tw0b = (unsigned short*)alloc((size_t)512 * ZDIM * 2);
  unsigned short* tw1b = (unsigned short*)alloc((size_t)256 * 512 * 2);
  unsigned short* h0   = (unsigned short*)alloc((size_t)BATCH * 512 * 2);
  unsigned short* h1   = (unsigned short*)alloc((size_t)BATCH * 256 * 2);
  unsigned short* z    = (unsigned short*)alloc((size_t)BATCH * ZDIM * 2);
  unsigned short* z1   = (unsigned short*)alloc((size_t)BATCH * 512 * 2);
  unsigned short* z2   = (unsigned short*)alloc((size_t)BATCH * 256 * 2);

  // fused cast + embedding pooling (z[:, 64:1728])
  {
    CastArgs a;
    a.s[0] = x_dense; a.d[0] = xdb;  a.n4[0] = BATCH * 256 / 4;
    a.s[1] = bw0;     a.d[1] = bw0b; a.n4[1] = 512 * 256 / 4;
    a.s[2] = bw1;     a.d[2] = bw1b; a.n4[2] = 256 * 512 / 4;
    a.s[3] = bw2;     a.d[3] = bw2b; a.n4[3] = 64 * 256 / 4;
    a.s[4] = tw0;     a.d[4] = tw0b; a.n4[4] = 512 * ZDIM / 4;
    a.s[5] = tw1;     a.d[5] = tw1b; a.n4[5] = 256 * 512 / 4;
    a.total = a.n4[0] + a.n4[1] + a.n4[2] + a.n4[3] + a.n4[4] + a.n4[5];
    embed_cast<<<CAST_BLOCKS + EMBED_BLOCKS, 256, 0, stream>>>(a, x_idx, tables, z);
  }

  auto gemm = [&](const unsigned short* A, const unsigned short* W, const float* bias,
                  unsigned short* C, int M, int N, int K, int ldc, int relu) {
    if (N >= 128) {
      int blocks = (M >> 6) * (N >> 6);
      if (relu)
        gemm64s<1><<<blocks, 256, 0, stream>>>(A, W, bias, C, M, N, K, ldc);
      else
        gemm64s<0><<<blocks, 256, 0, stream>>>(A, W, bias, C, M, N, K, ldc);
    } else {
      int tiles = (M >> 4) * (N >> 4);
      if (relu)
        gemm16<1><<<tiles / 4, 256, 0, stream>>>(A, W, bias, C, M, N, K, ldc);
      else
        gemm16<0><<<tiles / 4, 256, 0, stream>>>(A, W, bias, C, M, N, K, ldc);
    }
  };

  // bottom MLP
  gemm(xdb, bw0b, bb0, h0, BATCH, 512, 256, 512, 1);
  gemm(h0,  bw1b, bb1, h1, BATCH, 256, 512, 256, 1);
  gemm(h1,  bw2b, bb2, z,  BATCH, 64, 256, ZDIM, 1);   // into z[:,0:64]

  // top MLP
  gemm(z,  tw0b, tb0, z1, BATCH, 512, ZDIM, 512, 1);
  gemm(z1, tw1b, tb1, z2, BATCH, 256, 512, 256, 1);

  final_layer<<<BATCH / 4, 256, 0, stream>>>(z2, tw2, tb2, out);
}

// Round 5
// 177.089 us; speedup vs baseline: 1.6354x; 1.0291x over previous
//
#include <hip/hip_runtime.h>
#include <hip/hip_bf16.h>
#include <math.h>

typedef __attribute__((ext_vector_type(8))) short short8;
typedef __attribute__((ext_vector_type(4))) float f32x4;

#define NUM_TABLES 26
#define ROWS 100000
#define EMB 64
#define BATCH 4096
#define LOOKUPS 32
#define ZDIM 1728  // 64*(1+26)

#define CAST_BLOCKS 128
#define BOT_BLOCKS 256                       // 16 batch rows each
#define EMBED_BLOCKS (NUM_TABLES * BATCH / 4)

__device__ __forceinline__ unsigned short f2bf(float f) {
  unsigned int u = __float_as_uint(f);
  u += 0x7FFFu + ((u >> 16) & 1u);   // round-to-nearest-even
  return (unsigned short)(u >> 16);
}
__device__ __forceinline__ float bf2f(unsigned short h) {
  return __uint_as_float(((unsigned int)h) << 16);
}

__device__ __forceinline__ void gload16(const void* g, void* l) {
  __builtin_amdgcn_global_load_lds(
      (const __attribute__((address_space(1))) void*)g,
      (__attribute__((address_space(3))) void*)l, 16, 0, 0);
}

// B-fragment for mfma_16x16x32_bf16 straight from an f32 weight matrix W[N][K]:
// lane l holds W[colbase + (l&15)][kc*32 + (l>>4)*8 + j], j=0..7, converted bf16.
__device__ __forceinline__ short8 wfrag_f32(const float* __restrict__ W, int K,
                                            int colbase, int l, int kc) {
  const float* p = W + (size_t)(colbase + (l & 15)) * K + kc * 32 + ((l >> 4) << 3);
  float4 u = *(const float4*)p;
  float4 v = *(const float4*)(p + 4);
  short8 f;
  f[0] = (short)f2bf(u.x); f[1] = (short)f2bf(u.y);
  f[2] = (short)f2bf(u.z); f[3] = (short)f2bf(u.w);
  f[4] = (short)f2bf(v.x); f[5] = (short)f2bf(v.y);
  f[6] = (short)f2bf(v.z); f[7] = (short)f2bf(v.w);
  return f;
}

struct MegaArgs {
  const float* cast_s[2];           // tw0, tw1
  unsigned short* cast_d[2];
  int cast_n4[2];
  int cast_total;
  const float* x_dense;
  const float* bw0; const float* bb0;
  const float* bw1; const float* bb1;
  const float* bw2; const float* bb2;
  const int* idx;
  const float* tables;
  unsigned short* z;
};

// ---- mega kernel: 3 block roles ----
// [0, CAST_BLOCKS): cast top weights f32->bf16
// [CAST_BLOCKS, +BOT_BLOCKS): bottom MLP for 16 batch rows, block-local
// rest: EmbeddingBag sum (wave per bag)
__global__ void mega(MegaArgs a) {
  // bot-role LDS (statically allocated for all blocks; 24 KiB)
  __shared__ unsigned short xb[16][256];   // x bf16, then h1 (bot1 out)
  __shared__ unsigned short h0[16][512];   // bot0 out

  if (blockIdx.x < CAST_BLOCKS) {
    for (int i = blockIdx.x * blockDim.x + threadIdx.x; i < a.cast_total;
         i += CAST_BLOCKS * blockDim.x) {
      int r = i;
      #pragma unroll
      for (int sg = 0; sg < 2; ++sg) {
        if (r < a.cast_n4[sg]) {
          float4 v = ((const float4*)a.cast_s[sg])[r];
          ushort4 o;
          o.x = f2bf(v.x); o.y = f2bf(v.y); o.z = f2bf(v.z); o.w = f2bf(v.w);
          ((ushort4*)a.cast_d[sg])[r] = o;
          break;
        }
        r -= a.cast_n4[sg];
      }
    }
    return;
  }

  if (blockIdx.x < CAST_BLOCKS + BOT_BLOCKS) {
    // ---- bottom MLP role: rows [b0, b0+16) ----
    int b0 = (int)(blockIdx.x - CAST_BLOCKS) << 4;
    int w = threadIdx.x >> 6;       // wave 0..3
    int l = threadIdx.x & 63;

    // stage x f32 -> bf16 LDS, XOR-swizzled 16B chunks: chunk' = chunk ^ (row&7)
    #pragma unroll
    for (int i = 0; i < 4; ++i) {
      int flat = i * 256 + threadIdx.x;     // float4 id, 0..1023
      int row = flat >> 6;                  // 64 float4 per row
      int c4 = flat & 63;
      float4 v = *(const float4*)(a.x_dense + (size_t)(b0 + row) * 256 + c4 * 4);
      int chunk = c4 >> 1;
      int scol = ((chunk ^ (row & 7)) << 3) | ((c4 & 1) << 2);
      ushort4 o;
      o.x = f2bf(v.x); o.y = f2bf(v.y); o.z = f2bf(v.z); o.w = f2bf(v.w);
      *(ushort4*)&xb[row][scol] = o;
    }
    __syncthreads();

    int arow = l & 15;
    int sA = arow & 7;
    const char* xbp = (const char*)&xb[0][0];
    const char* h0p = (const char*)&h0[0][0];

    // ---- bot0: h0[16][512] = relu(x @ W0^T + b0), K=256 ----
    f32x4 acc0[8];
    #pragma unroll
    for (int n = 0; n < 8; ++n) acc0[n] = (f32x4){0.f, 0.f, 0.f, 0.f};
    for (int kc = 0; kc < 8; ++kc) {
      int c = kc * 4 + (l >> 4);
      short8 av = *(const short8*)(xbp + arow * 512 + ((c ^ sA) << 4));
      #pragma unroll
      for (int n = 0; n < 8; ++n) {
        short8 bv = wfrag_f32(a.bw0, 256, w * 128 + n * 16, l, kc);
        acc0[n] = __builtin_amdgcn_mfma_f32_16x16x32_bf16(av, bv, acc0[n], 0, 0, 0);
      }
    }
    #pragma unroll
    for (int n = 0; n < 8; ++n) {
      int col = w * 128 + n * 16 + (l & 15);
      float bv = a.bb0[col];
      int chunk = col >> 3;
      #pragma unroll
      for (int r = 0; r < 4; ++r) {
        int row = ((l >> 4) << 2) + r;
        float val = acc0[n][r] + bv;
        val = val > 0.f ? val : 0.f;
        h0[row][((chunk ^ (row & 7)) << 3) | (col & 7)] = f2bf(val);
      }
    }
    __syncthreads();

    // ---- bot1: h1[16][256] = relu(h0 @ W1^T + b1), K=512 -> into xb ----
    f32x4 acc1[4];
    #pragma unroll
    for (int n = 0; n < 4; ++n) acc1[n] = (f32x4){0.f, 0.f, 0.f, 0.f};
    for (int kc = 0; kc < 16; ++kc) {
      int c = kc * 4 + (l >> 4);
      short8 av = *(const short8*)(h0p + arow * 1024 + ((c ^ sA) << 4));
      #pragma unroll
      for (int n = 0; n < 4; ++n) {
        short8 bv = wfrag_f32(a.bw1, 512, w * 64 + n * 16, l, kc);
        acc1[n] = __builtin_amdgcn_mfma_f32_16x16x32_bf16(av, bv, acc1[n], 0, 0, 0);
      }
    }
    __syncthreads();     // everyone done reading xb (bot0 A-frags long done; safe to overwrite)
    #pragma unroll
    for (int n = 0; n < 4; ++n) {
      int col = w * 64 + n * 16 + (l & 15);
      float bv = a.bb1[col];
      int chunk = col >> 3;
      #pragma unroll
      for (int r = 0; r < 4; ++r) {
        int row = ((l >> 4) << 2) + r;
        float val = acc1[n][r] + bv;
        val = val > 0.f ? val : 0.f;
        xb[row][((chunk ^ (row & 7)) << 3) | (col & 7)] = f2bf(val);
      }
    }
    __syncthreads();

    // ---- bot2: z[b,0:64] = relu(h1 @ W2^T + b2), K=256 ----
    f32x4 acc2 = (f32x4){0.f, 0.f, 0.f, 0.f};
    for (int kc = 0; kc < 8; ++kc) {
      int c = kc * 4 + (l >> 4);
      short8 av = *(const short8*)(xbp + arow * 512 + ((c ^ sA) << 4));
      short8 bv = wfrag_f32(a.bw2, 256, w * 16, l, kc);
      acc2 = __builtin_amdgcn_mfma_f32_16x16x32_bf16(av, bv, acc2, 0, 0, 0);
    }
    {
      int col = w * 16 + (l & 15);
      float bv = a.bb2[col];
      #pragma unroll
      for (int r = 0; r < 4; ++r) {
        int row = ((l >> 4) << 2) + r;
        float val = acc2[r] + bv;
        val = val > 0.f ? val : 0.f;
        a.z[(size_t)(b0 + row) * ZDIM + col] = f2bf(val);
      }
    }
    return;
  }

  // ---- embedding role: one wave per bag, float4/lane, 4 rows/iter ----
  int g = (int)(((blockIdx.x - CAST_BLOCKS - BOT_BLOCKS) << 2) + (threadIdx.x >> 6));
  int lane = threadIdx.x & 63;
  int t = g >> 12;          // / BATCH
  int b = g & 4095;
  const int* ip = a.idx + ((size_t)t * BATCH + b) * LOOKUPS;
  int myidx = (lane < LOOKUPS) ? ip[lane] : 0;
  const float* tbl = a.tables + (size_t)t * ROWS * EMB;
  int grp = lane >> 4;      // lookup sub-group 0..3
  int e4 = lane & 15;       // float4 index within row
  float4 acc = {0.f, 0.f, 0.f, 0.f};
  #pragma unroll
  for (int it = 0; it < 8; ++it) {
    int r = __shfl(myidx, it * 4 + grp, 64);
    float4 v = ((const float4*)(tbl + (size_t)r * EMB))[e4];
    acc.x += v.x; acc.y += v.y; acc.z += v.z; acc.w += v.w;
  }
  #pragma unroll
  for (int m = 16; m <= 32; m <<= 1) {
    acc.x += __shfl_xor(acc.x, m, 64);
    acc.y += __shfl_xor(acc.y, m, 64);
    acc.z += __shfl_xor(acc.z, m, 64);
    acc.w += __shfl_xor(acc.w, m, 64);
  }
  if (lane < 16) {
    ushort4 o;
    o.x = f2bf(acc.x); o.y = f2bf(acc.y); o.z = f2bf(acc.z); o.w = f2bf(acc.w);
    *(ushort4*)&a.z[(size_t)b * ZDIM + EMB + t * EMB + e4 * 4] = o;
  }
}

// ---- block GEMM (m97 single-buffer schedule): C = act(A @ W^T + bias) ----
// 64x64 tile / 256-thread block, K-step 64. global_load_lds staging (linear
// LDS dest); bank-swizzle via pre-swizzled GLOBAL source, same XOR on read.
template<int ACT>  // 0 = none, 1 = relu
__global__ __launch_bounds__(256) void gemm64s(
    const unsigned short* __restrict__ A,
    const unsigned short* __restrict__ W,
    const float* __restrict__ bias,
    unsigned short* __restrict__ C,
    int M, int N, int K, int ldc) {
  __shared__ unsigned short lds[2][64][64];  // [A=0/B=1][row][col], 16 KiB

  int t = threadIdx.x;
  int lane = t & 63;
  int wid = t >> 6;
  int wr = wid >> 1;        // 0..1
  int wc = wid & 1;         // 0..1

  int ntn = N >> 6;
  int tm = blockIdx.x / ntn;
  int tn = blockIdx.x - tm * ntn;

  int srow = lane >> 3;
  int schunk = (lane & 7) ^ (srow & 7);
  const unsigned short* Ap0 = A + (size_t)(tm * 64 + wid * 16 + srow) * K + schunk * 8;
  const unsigned short* Wp0 = W + (size_t)(tn * 64 + wid * 16 + srow) * K + schunk * 8;
  size_t rowK8 = (size_t)8 * K;

  f32x4 acc[2][2];
  #pragma unroll
  for (int m = 0; m < 2; ++m)
    #pragma unroll
    for (int n = 0; n < 2; ++n)
      acc[m][n] = (f32x4){0.f, 0.f, 0.f, 0.f};

  int ra = wr * 32 + (lane & 15);
  int rb = wc * 32 + (lane & 15);
  int cidx = lane >> 4;
  int sA = ra & 7, sB = rb & 7;

  for (int k0 = 0; k0 < K; k0 += 64) {
    #pragma unroll
    for (int j = 0; j < 2; ++j) {
      gload16(Ap0 + (size_t)k0 + j * rowK8, &lds[0][wid * 16 + j * 8][0]);
      gload16(Wp0 + (size_t)k0 + j * rowK8, &lds[1][wid * 16 + j * 8][0]);
    }
    __syncthreads();

    const char* bA = (const char*)&lds[0][0][0];
    const char* bB = (const char*)&lds[1][0][0];
    #pragma unroll
    for (int kc = 0; kc < 2; ++kc) {
      int c = kc * 4 + cidx;
      short8 a0 = *(const short8*)(bA + ra * 128 + ((c ^ sA) << 4));
      short8 a1 = *(const short8*)(bA + (ra + 16) * 128 + ((c ^ sA) << 4));
      short8 b0 = *(const short8*)(bB + rb * 128 + ((c ^ sB) << 4));
      short8 b1 = *(const short8*)(bB + (rb + 16) * 128 + ((c ^ sB) << 4));
      acc[0][0] = __builtin_amdgcn_mfma_f32_16x16x32_bf16(a0, b0, acc[0][0], 0, 0, 0);
      acc[0][1] = __builtin_amdgcn_mfma_f32_16x16x32_bf16(a0, b1, acc[0][1], 0, 0, 0);
      acc[1][0] = __builtin_amdgcn_mfma_f32_16x16x32_bf16(a1, b0, acc[1][0], 0, 0, 0);
      acc[1][1] = __builtin_amdgcn_mfma_f32_16x16x32_bf16(a1, b1, acc[1][1], 0, 0, 0);
    }
    __syncthreads();
  }

  #pragma unroll
  for (int m = 0; m < 2; ++m) {
    int drow = tm * 64 + wr * 32 + m * 16 + ((lane >> 4) << 2);
    #pragma unroll
    for (int n = 0; n < 2; ++n) {
      int dcol = tn * 64 + wc * 32 + n * 16 + (lane & 15);
      float bv = bias[dcol];
      #pragma unroll
      for (int r = 0; r < 4; ++r) {
        float v = acc[m][n][r] + bv;
        if (ACT == 1) v = v > 0.f ? v : 0.f;
        C[(size_t)(drow + r) * ldc + dcol] = f2bf(v);
      }
    }
  }
}

// ---- final layer: out[b] = sigmoid(dot(z2[b,0:256], w) + bias) ----
__global__ void final_layer(const unsigned short* __restrict__ z2,
                            const float* __restrict__ w,
                            const float* __restrict__ bias,
                            float* __restrict__ out) {
  int g = (int)((blockIdx.x * blockDim.x + threadIdx.x) >> 6);  // sample
  int lane = threadIdx.x & 63;
  const unsigned short* zp = z2 + (size_t)g * 256;
  float s = 0.f;
  #pragma unroll
  for (int k = 0; k < 256; k += 64)
    s += bf2f(zp[k + lane]) * w[k + lane];
  #pragma unroll
  for (int off = 32; off > 0; off >>= 1)
    s += __shfl_down(s, off, 64);
  if (lane == 0) out[g] = 1.f / (1.f + expf(-(s + bias[0])));
}

extern "C" void kernel_launch(void* const* d_in, const int* in_sizes, int n_in,
                              void* d_out, int out_size, void* d_ws, size_t ws_size,
                              hipStream_t stream) {
  const float* x_dense = (const float*)d_in[0];
  const int*   x_idx   = (const int*)d_in[1];
  const float* tables  = (const float*)d_in[2];
  const float* bw0 = (const float*)d_in[3];  const float* bb0 = (const float*)d_in[4];
  const float* bw1 = (const float*)d_in[5];  const float* bb1 = (const float*)d_in[6];
  const float* bw2 = (const float*)d_in[7];  const float* bb2 = (const float*)d_in[8];
  const float* tw0 = (const float*)d_in[9];  const float* tb0 = (const float*)d_in[10];
  const float* tw1 = (const float*)d_in[11]; const float* tb1 = (const float*)d_in[12];
  const float* tw2 = (const float*)d_in[13]; const float* tb2 = (const float*)d_in[14];
  float* out = (float*)d_out;

  char* ws = (char*)d_ws;
  size_t off = 0;
  auto alloc = [&](size_t bytes) { void* p = ws + off; off += (bytes + 255) & ~(size_t)255; return p; };
  unsigned short* tw0b = (unsigned short*)alloc((size_t)512 * ZDIM * 2);
  unsigned short* tw1b = (unsigned short*)alloc((size_t)256 * 512 * 2);
  unsigned short* z    = (unsigned short*)alloc((size_t)BATCH * ZDIM * 2);
  unsigned short* z1   = (unsigned short*)alloc((size_t)BATCH * 512 * 2);
  unsigned short* z2   = (unsigned short*)alloc((size_t)BATCH * 256 * 2);

  // mega: cast(tw0,tw1) + bottom MLP (z[:,0:64]) + embedding (z[:,64:])
  {
    MegaArgs a;
    a.cast_s[0] = tw0; a.cast_d[0] = tw0b; a.cast_n4[0] = 512 * ZDIM / 4;
    a.cast_s[1] = tw1; a.cast_d[1] = tw1b; a.cast_n4[1] = 256 * 512 / 4;
    a.cast_total = a.cast_n4[0] + a.cast_n4[1];
    a.x_dense = x_dense;
    a.bw0 = bw0; a.bb0 = bb0;
    a.bw1 = bw1; a.bb1 = bb1;
    a.bw2 = bw2; a.bb2 = bb2;
    a.idx = x_idx;
    a.tables = tables;
    a.z = z;
    mega<<<CAST_BLOCKS + BOT_BLOCKS + EMBED_BLOCKS, 256, 0, stream>>>(a);
  }

  auto gemm = [&](const unsigned short* A, const unsigned short* W, const float* bias,
                  unsigned short* C, int M, int N, int K, int ldc, int relu) {
    int blocks = (M >> 6) * (N >> 6);
    if (relu)
      gemm64s<1><<<blocks, 256, 0, stream>>>(A, W, bias, C, M, N, K, ldc);
    else
      gemm64s<0><<<blocks, 256, 0, stream>>>(A, W, bias, C, M, N, K, ldc);
  };

  // top MLP
  gemm(z,  tw0b, tb0, z1, BATCH, 512, ZDIM, 512, 1);
  gemm(z1, tw1b, tb1, z2, BATCH, 256, 512, 256, 1);

  final_layer<<<BATCH / 4, 256, 0, stream>>>(z2, tw2, tb2, out);
}